// Round 11
// baseline (246.151 us; speedup 1.0000x reference)
//
#include <hip/hip_runtime.h>

// MoE: M=4096, K=1024, E=8, N=1024, TOPK=2
// out[m] = sum_t topk_w[m,t] * ( silu(hs[m]@w1[e][:, :N]) * (hs[m]@w1[e][:, N:]) ) @ w2[e]
//
// Ledger r0-r10 (clean r10 profile: GEMM1 58.1us / GEMM2 58.6us / prep <58 /
// gather ~6 / replay residual ~50):
//   Per-step arithmetic: 576 blk x 16 steps / 256 CU @ 58us = ~2000 cyc/step,
//   MFMA only ~320 -> the __syncthreads vmcnt(0) drain re-exposes stage
//   latency EVERY k-step. r1 (dbuf+drain) null; r3 (counted+8 barriers/tile)
//   -9us; r6 atomics -56; r9 forced-occupancy spill -91.
// r11: the untested cell -- counted vmcnt (never 0 mid-loop, depth-2, NBUF=3)
//   x coarse 2-barrier k-steps x 512-thread blocks (8 waves = same 2/SIMD as
//   today; per-wave acc[NB][4][2] keeps VGPR ~130, no spill).

#define M_TOK   4096
#define K_DIM   1024
#define N_DIM   1024
#define E_NUM   8
#define NPAIR   8192            // M_TOK * TOPK
#define BM      128
#define ROWS_CAP 9216           // NPAIR + E_NUM*BM
#define NROWBLK 72              // ROWS_CAP / BM  (divisible by 8 -> bijective XCD swizzle)

typedef unsigned short u16;
typedef unsigned int   u32;
typedef __attribute__((ext_vector_type(8))) short bf16x8;
typedef __attribute__((ext_vector_type(4))) float f32x4;

#define GPTR(p) ((const __attribute__((address_space(1))) u32*)(const void*)(p))
#define LPTR(p) ((__attribute__((address_space(3))) u32*)(void*)(p))
#define VMW(n) asm volatile("s_waitcnt vmcnt(" #n ")" ::: "memory")

__device__ __forceinline__ u16 f2bf(float f) {
  union { float f; u32 u; } v; v.f = f;
  u32 r = v.u + 0x7FFFu + ((v.u >> 16) & 1u);   // RNE
  return (u16)(r >> 16);
}
__device__ __forceinline__ float bf2f(u16 u) {
  union { u32 u; float f; } v; v.u = ((u32)u) << 16;
  return v.f;
}

// ---------------- fused prep: routing + hs convert + w1/w2 transposes ---------
// (unchanged from r10 frontier; r8 proved splitting costs ~13us)
__device__ __forceinline__ void transpose_tile64(
    const float* __restrict__ src, u16* __restrict__ dst, int R, int Cc,
    int rb, int cb, void* shm) {
  float* lds = (float*)shm;                  // [64][67]: pad -> <=2-way (free)
  const int r0 = rb * 64, c0 = cb * 64;
  const int t = threadIdx.x;
#pragma unroll
  for (int it = 0; it < 4; ++it) {
    int lin = it * 256 + t;
    int rr = lin >> 4, c4 = (lin & 15) << 2;
    float4 v = *(const float4*)&src[(size_t)(r0 + rr) * Cc + c0 + c4];
    lds[rr * 67 + c4 + 0] = v.x; lds[rr * 67 + c4 + 1] = v.y;
    lds[rr * 67 + c4 + 2] = v.z; lds[rr * 67 + c4 + 3] = v.w;
  }
  __syncthreads();
#pragma unroll
  for (int it = 0; it < 4; ++it) {
    int lin = it * 256 + t;
    int cc = lin >> 4, r4 = (lin & 15) << 2;
    ushort4 o;
    o.x = f2bf(lds[(r4 + 0) * 67 + cc]);
    o.y = f2bf(lds[(r4 + 1) * 67 + cc]);
    o.z = f2bf(lds[(r4 + 2) * 67 + cc]);
    o.w = f2bf(lds[(r4 + 3) * 67 + cc]);
    *(ushort4*)&dst[(size_t)(c0 + cc) * R + r0 + r4] = o;
  }
}

__global__ __launch_bounds__(256) void prep_route_kernel(
    const float* __restrict__ hs, const float* __restrict__ w1,
    const float* __restrict__ w2, const int* __restrict__ topk_ids,
    u16* __restrict__ hsb, u16* __restrict__ w1t, u16* __restrict__ w2t,
    int* __restrict__ pair_token, int* __restrict__ pos_of,
    int* __restrict__ block_expert) {
  __shared__ __align__(16) char shm[17408];
  const int bid = blockIdx.x;
  const int t = threadIdx.x;
  if (bid == 0) {
    int* lcnt = (int*)shm;                   // [256][8]
    __shared__ int cnt[E_NUM], off[E_NUM], pad[E_NUM];
    int c[E_NUM];
#pragma unroll
    for (int e = 0; e < E_NUM; ++e) c[e] = 0;
    for (int i = 0; i < 32; ++i) c[topk_ids[t * 32 + i] & 7]++;
#pragma unroll
    for (int e = 0; e < E_NUM; ++e) lcnt[t * 8 + e] = c[e];
    __syncthreads();
    if (t < E_NUM) {
      int run = 0;
      for (int i = 0; i < 256; ++i) {
        int v = lcnt[i * 8 + t]; lcnt[i * 8 + t] = run; run += v;
      }
      cnt[t] = run;
    }
    __syncthreads();
    if (t == 0) {
      int run = 0, blk = 0;
      for (int e = 0; e < E_NUM; ++e) {
        off[e] = run;
        int padded = ((cnt[e] + BM - 1) / BM) * BM;
        pad[e] = padded;
        for (int b = 0; b < padded / BM; ++b) block_expert[blk++] = e;
        run += padded;
      }
      for (; blk < NROWBLK; ++blk) block_expert[blk] = -1;
    }
    __syncthreads();
    for (int i = 0; i < 32; ++i) {
      int p = t * 32 + i;
      int e = topk_ids[p] & 7;
      int idx = t * 8 + e;
      int pos = off[e] + lcnt[idx];
      lcnt[idx] = lcnt[idx] + 1;
      pair_token[pos] = p >> 1;
      pos_of[p] = pos;
    }
    for (int e = 0; e < E_NUM; ++e) {
      int s = off[e] + cnt[e], epos = off[e] + pad[e];
      for (int r = s + t; r < epos; r += 256) pair_token[r] = 0;
    }
  } else if (bid <= 4096) {
    int i = (bid - 1) * 256 + t;
    float4 v = ((const float4*)hs)[i];
    ushort4 o;
    o.x = f2bf(v.x); o.y = f2bf(v.y); o.z = f2bf(v.z); o.w = f2bf(v.w);
    ((ushort4*)hsb)[i] = o;
  } else if (bid <= 8192) {
    int idx = bid - 4097;
    int e = idx >> 9, rem = idx & 511;
    int cb = rem >> 4, rb = rem & 15;
    transpose_tile64(w1 + (size_t)e * 1024 * 2048, w1t + (size_t)e * 1024 * 2048,
                     1024, 2048, rb, cb, shm);
  } else {
    int idx = bid - 8193;
    int e = idx >> 8, rem = idx & 255;
    int cb = rem >> 4, rb = rem & 15;
    transpose_tile64(w2 + (size_t)e * 1024 * 1024, w2t + (size_t)e * 1024 * 1024,
                     1024, 1024, rb, cb, shm);
  }
}

// ---------------- grouped GEMM, 128x128(xNB), counted-vmcnt 2-barrier steps ---
// NB=2: fused gate|up GEMM1 -> h = silu(gate)*up.  NB=1: plain GEMM2 -> y.
// 512 threads / 8 waves (2Mx4C), per-wave 64 rows x 32 cols x NB, acc[NB][4][2]
// (~130 VGPR, no spill; launch_bounds(512,2) caps at 256/wave). NBUF=3 LDS
// (GEMM1 144KB, GEMM2 96KB -> 1 block/CU, 8 waves = 2/SIMD, same as r10).
// K-step: {stage tile t+2 -> vmcnt(12) [2 tiles stay in flight, NEVER 0
// mid-loop] -> s_barrier -> 2xks {ds_read frags, MFMA cluster} -> s_barrier}.
// Buffer rotation/wait logic mirrors r3's refcheck-PASSED kernel; only the
// phase granularity differs (2 barriers/tile vs r3's 8 -- r3's overhead).
// sched_barrier(0) after each raw barrier pins compiler memory ordering.
// XCD chunk swizzle (T1): 72 % 8 == 0 -> bx = (b&7)*9 + (b>>3) bijective.
template <bool GATHER, int NB>
__global__ __launch_bounds__(512, 2) void gemm_cnt(
    const u16* __restrict__ A, const u16* __restrict__ Bt, u16* __restrict__ Out,
    const int* __restrict__ pair_token, const int* __restrict__ block_expert) {
  constexpr int AE = 128 * 64;             // elems per A tile (16 KB)
  constexpr int BE = NB * 128 * 64;        // elems per B tile (NB*16 KB)
  constexpr int KT = K_DIM / 64;           // 16 k-steps

  const int bx = ((int)blockIdx.x & 7) * (NROWBLK / 8) + ((int)blockIdx.x >> 3);
  const int e = block_expert[bx];
  if (e < 0) return;
  const int by = blockIdx.y;

  extern __shared__ __align__(16) u16 smem[];
  u16* As = smem;                          // 3 * AE
  u16* Bs = smem + 3 * AE;                 // 3 * BE

  const int tid = threadIdx.x;
  const int wave = tid >> 6;               // 0..7
  const int lane = tid & 63;
  const int wr  = wave >> 2;               // 0..1 (64-row half)
  const int wcc = wave & 3;                // 0..3 (32-col group)
  const int srow = wave * 8 + (lane >> 3); // 0..63 staging row in 64-row shot
  const int kc = ((lane & 7) ^ (srow & 7)) << 3;  // pre-swizzled global chunk

  const u16* ap[2];
#pragma unroll
  for (int is = 0; is < 2; ++is) {
    int rt = is * 64 + srow;
    int grow = bx * BM + rt;
    int arow = GATHER ? pair_token[grow] : grow;
    ap[is] = A + (size_t)arow * K_DIM + kc;
  }
  const u16* bp[NB * 2];
  const u16* base_e = Bt + (size_t)e * (NB * N_DIM) * K_DIM;
#pragma unroll
  for (int is = 0; is < NB * 2; ++is) {
    int rt = is * 64 + srow;
    int nb = rt >> 7;
    int n = nb * N_DIM + by * 128 + (rt & 127);
    bp[is] = base_e + (size_t)n * K_DIM + kc;
  }

  // per-wave loads per tile: A 2 + B NB*2  (GEMM1: 6, GEMM2: 4)
#define STAGE(buf, koff) do { \
    _Pragma("unroll") \
    for (int is_ = 0; is_ < 2; ++is_) \
      __builtin_amdgcn_global_load_lds(GPTR(ap[is_] + (koff)), \
          LPTR(&As[(buf) * AE + is_ * 4096 + wave * 512]), 16, 0, 0); \
    _Pragma("unroll") \
    for (int is_ = 0; is_ < NB * 2; ++is_) \
      __builtin_amdgcn_global_load_lds(GPTR(bp[is_] + (koff)), \
          LPTR(&Bs[(buf) * BE + is_ * 4096 + wave * 512]), 16, 0, 0); \
  } while (0)

  f32x4 acc[NB][4][2];
#pragma unroll
  for (int nb = 0; nb < NB; ++nb)
#pragma unroll
    for (int i = 0; i < 4; ++i)
#pragma unroll
      for (int j = 0; j < 2; ++j) acc[nb][i][j] = f32x4{0.f, 0.f, 0.f, 0.f};

  // prologue: tiles 0,1 in flight
  STAGE(0, 0);
  STAGE(1, 64);

  int cur = 0, nxt = 2;
  for (int t = 0; t < KT; ++t) {
    if (t < KT - 2) STAGE(nxt, (t + 2) * 64);
    // wait for tile t only; keep up to 2 tiles (t+1,t+2) in flight
    if constexpr (NB == 2) {
      if (t < KT - 2) VMW(12);
      else if (t == KT - 2) VMW(6);
      else VMW(0);
    } else {
      if (t < KT - 2) VMW(8);
      else if (t == KT - 2) VMW(4);
      else VMW(0);
    }
    __builtin_amdgcn_s_barrier();
    __builtin_amdgcn_sched_barrier(0);
    const u16* Ab = &As[cur * AE];
    const u16* Bb = &Bs[cur * BE];
#pragma unroll
    for (int ks = 0; ks < 2; ++ks) {
      const int cq = ks * 4 + (lane >> 4);
      bf16x8 af[4], bfr[NB][2];
#pragma unroll
      for (int i = 0; i < 4; ++i) {
        int row = wr * 64 + i * 16 + (lane & 15);
        af[i] = *(const bf16x8*)&Ab[row * 64 + ((cq ^ (row & 7)) << 3)];
      }
#pragma unroll
      for (int nb = 0; nb < NB; ++nb)
#pragma unroll
        for (int j = 0; j < 2; ++j) {
          int n = wcc * 32 + j * 16 + (lane & 15);
          bfr[nb][j] = *(const bf16x8*)&Bb[nb * 8192 + n * 64 + ((cq ^ (n & 7)) << 3)];
        }
#pragma unroll
      for (int nb = 0; nb < NB; ++nb)
#pragma unroll
        for (int i = 0; i < 4; ++i)
#pragma unroll
          for (int j = 0; j < 2; ++j)
            acc[nb][i][j] = __builtin_amdgcn_mfma_f32_16x16x32_bf16(af[i], bfr[nb][j], acc[nb][i][j], 0, 0, 0);
    }
    __builtin_amdgcn_s_barrier();            // all reads of cur done before it
    __builtin_amdgcn_sched_barrier(0);       //   becomes a stage target again
    cur = (cur == 2) ? 0 : cur + 1;
    nxt = (nxt == 2) ? 0 : nxt + 1;
  }
#undef STAGE

  // epilogue: C/D layout col=lane&15, row=(lane>>4)*4+reg (m89/m91-verified)
  const size_t rbase = (size_t)bx * BM + wr * 64 + ((lane >> 4) * 4);
  const int cbase = by * 128 + wcc * 32 + (lane & 15);
#pragma unroll
  for (int i = 0; i < 4; ++i)
#pragma unroll
    for (int j = 0; j < 2; ++j)
#pragma unroll
      for (int r = 0; r < 4; ++r) {
        float v;
        if (NB == 2) {
          float g = acc[0][i][j][r], u = acc[1][i][j][r];
          v = g * u / (1.f + __expf(-g));
        } else {
          v = acc[0][i][j][r];
        }
        Out[(rbase + i * 16 + r) * N_DIM + cbase + j * 16] = f2bf(v);
      }
}

// ---------------- gather: out[m] = w0*y[pos0] + w1*y[pos1] --------------------
__global__ __launch_bounds__(256) void gather_kernel(
    const u16* __restrict__ y, const float* __restrict__ tw,
    const int* __restrict__ pos_of, float* __restrict__ out) {
  int m = blockIdx.x;
  int k = threadIdx.x * 4;
  int p0 = pos_of[m * 2 + 0], p1 = pos_of[m * 2 + 1];
  float w0 = tw[m * 2 + 0], w1 = tw[m * 2 + 1];
  ushort4 y0 = *(const ushort4*)&y[(size_t)p0 * 1024 + k];
  ushort4 y1 = *(const ushort4*)&y[(size_t)p1 * 1024 + k];
  float4 o;
  o.x = w0 * bf2f(y0.x) + w1 * bf2f(y1.x);
  o.y = w0 * bf2f(y0.y) + w1 * bf2f(y1.y);
  o.z = w0 * bf2f(y0.z) + w1 * bf2f(y1.z);
  o.w = w0 * bf2f(y0.w) + w1 * bf2f(y1.w);
  *(float4*)&out[(size_t)m * 1024 + k] = o;
}

extern "C" void kernel_launch(void* const* d_in, const int* in_sizes, int n_in,
                              void* d_out, int out_size, void* d_ws, size_t ws_size,
                              hipStream_t stream) {
  const float* hs = (const float*)d_in[0];
  const float* w1 = (const float*)d_in[1];
  const float* w2 = (const float*)d_in[2];
  const float* tw = (const float*)d_in[3];
  const int* tids = (const int*)d_in[4];
  float* out = (float*)d_out;

  char* ws = (char*)d_ws;
  u16* hsb = (u16*)(ws);                                 //  8 MB  (M,K) bf16
  u16* w1t = (u16*)(ws + (size_t)(8u << 20));            // 32 MB  (E,2N,K) bf16
  u16* w2t = (u16*)(ws + (size_t)(40u << 20));           // 16 MB  (E,K,N)  bf16
  u16* h   = (u16*)(ws + (size_t)(56u << 20));           // 18.9 MB (ROWS_CAP,N)
  u16* y   = (u16*)(ws + (size_t)(76u << 20));           // 18.9 MB (ROWS_CAP,K)
  int* pair_token   = (int*)(ws + (size_t)(96u << 20));
  int* pos_of       = (int*)(ws + (size_t)(96u << 20) + 64 * 1024);
  int* block_expert = (int*)(ws + (size_t)(96u << 20) + 128 * 1024);

  // 4 dispatches: prep, GEMM1 (counted dbuf3), GEMM2 (counted dbuf3), gather
  size_t lds1 = (size_t)3 * (128 * 64 + 2 * 128 * 64) * sizeof(u16);  // 147456
  size_t lds2 = (size_t)3 * (128 * 64 + 1 * 128 * 64) * sizeof(u16);  //  98304
  prep_route_kernel<<<10241, 256, 0, stream>>>(
      hs, w1, w2, tids, hsb, w1t, w2t, pair_token, pos_of, block_expert);
  gemm_cnt<true, 2><<<dim3(NROWBLK, 8), 512, lds1, stream>>>(
      hsb, w1t, h, pair_token, block_expert);
  gemm_cnt<false, 1><<<dim3(NROWBLK, 8), 512, lds2, stream>>>(
      h, w2t, y, pair_token, block_expert);
  gather_kernel<<<4096, 256, 0, stream>>>(y, tw, pos_of, out);
}

// Round 12
// 237.077 us; speedup vs baseline: 1.0383x; 1.0383x over previous
//
#include <hip/hip_runtime.h>

// MoE: M=4096, K=1024, E=8, N=1024, TOPK=2
// out[m] = sum_t topk_w[m,t] * ( silu(hs[m]@w1[e][:, :N]) * (hs[m]@w1[e][:, N:]) ) @ w2[e]
//
// FINAL FRONTIER STATE (r4/r10-proven, 235.9/240.3us). Schedule matrix
// exhausted over r0-r11 -- seven GEMM variants, plateau 57-73us/GEMM:
//   serial-drain 64^2 (59) | dbuf 64^2 (59) | serial-drain 128^2 (57.5 BEST)
//   fine 8-phase (66) | forced-occ spill (127) | counted coarse dbuf3 (73)
// Mechanism: the winning config's 2-3 co-resident INDEPENDENT blocks hide
// each other's stage/drain latency (m114). Every LDS-for-pipeline trade cuts
// residency and loses more than it gains at this 576-block geometry.
// Floor: GEMM1 58 + GEMM2 58 + prep ~50 + gather 6 + gaps ~12 + replay ~50.
// Other disproven: gemm||transpose co-dispatch (r5, intermittent divergence),
// atomic scatter epilogue (r6, -56us), split prep (r8, -13us).

#define M_TOK   4096
#define K_DIM   1024
#define N_DIM   1024
#define E_NUM   8
#define NPAIR   8192            // M_TOK * TOPK
#define BM      128
#define ROWS_CAP 9216           // NPAIR + E_NUM*BM
#define NROWBLK 72              // ROWS_CAP / BM  (divisible by 8 -> bijective XCD swizzle)

typedef unsigned short u16;
typedef unsigned int   u32;
typedef __attribute__((ext_vector_type(8))) short bf16x8;
typedef __attribute__((ext_vector_type(4))) float f32x4;

#define GPTR(p) ((const __attribute__((address_space(1))) u32*)(const void*)(p))
#define LPTR(p) ((__attribute__((address_space(3))) u32*)(void*)(p))

__device__ __forceinline__ u16 f2bf(float f) {
  union { float f; u32 u; } v; v.f = f;
  u32 r = v.u + 0x7FFFu + ((v.u >> 16) & 1u);   // RNE
  return (u16)(r >> 16);
}
__device__ __forceinline__ float bf2f(u16 u) {
  union { u32 u; float f; } v; v.u = ((u32)u) << 16;
  return v.f;
}

// ---------------- fused prep: routing + hs convert + w1/w2 transposes ---------
// block 0            : routing (single block, deterministic p-order positions)
// blocks 1..4096     : hs fp32 -> bf16 flat convert (float4/lane)
// blocks 4097..8192  : w1 (E,K,2N) f32 -> w1t (E,2N,K) bf16 transpose tiles
// blocks 8193..10240 : w2 (E,N,K)  f32 -> w2t (E,K,N)  bf16 transpose tiles
__device__ __forceinline__ void transpose_tile64(
    const float* __restrict__ src, u16* __restrict__ dst, int R, int Cc,
    int rb, int cb, void* shm) {
  // LDS [64][67] f32: pad 67 -> write free, read <=2-way (free per m136).
  float* lds = (float*)shm;
  const int r0 = rb * 64, c0 = cb * 64;
  const int t = threadIdx.x;
#pragma unroll
  for (int it = 0; it < 4; ++it) {
    int lin = it * 256 + t;                  // 0..1023
    int rr = lin >> 4, c4 = (lin & 15) << 2;
    float4 v = *(const float4*)&src[(size_t)(r0 + rr) * Cc + c0 + c4];
    lds[rr * 67 + c4 + 0] = v.x; lds[rr * 67 + c4 + 1] = v.y;
    lds[rr * 67 + c4 + 2] = v.z; lds[rr * 67 + c4 + 3] = v.w;
  }
  __syncthreads();
#pragma unroll
  for (int it = 0; it < 4; ++it) {
    int lin = it * 256 + t;
    int cc = lin >> 4, r4 = (lin & 15) << 2;
    ushort4 o;
    o.x = f2bf(lds[(r4 + 0) * 67 + cc]);
    o.y = f2bf(lds[(r4 + 1) * 67 + cc]);
    o.z = f2bf(lds[(r4 + 2) * 67 + cc]);
    o.w = f2bf(lds[(r4 + 3) * 67 + cc]);
    *(ushort4*)&dst[(size_t)(c0 + cc) * R + r0 + r4] = o;
  }
}

__global__ __launch_bounds__(256) void prep_route_kernel(
    const float* __restrict__ hs, const float* __restrict__ w1,
    const float* __restrict__ w2, const int* __restrict__ topk_ids,
    u16* __restrict__ hsb, u16* __restrict__ w1t, u16* __restrict__ w2t,
    int* __restrict__ pair_token, int* __restrict__ pos_of,
    int* __restrict__ block_expert) {
  __shared__ __align__(16) char shm[17408];
  const int bid = blockIdx.x;
  const int t = threadIdx.x;
  if (bid == 0) {
    // ---- routing: hist + scan + assign, fused in one block ----
    int* lcnt = (int*)shm;                   // [256][8] per-thread expert counts
    __shared__ int cnt[E_NUM], off[E_NUM], pad[E_NUM];
    int c[E_NUM];
#pragma unroll
    for (int e = 0; e < E_NUM; ++e) c[e] = 0;
    // thread t owns pairs [t*32, t*32+32) -> deterministic p-order
    for (int i = 0; i < 32; ++i) c[topk_ids[t * 32 + i] & 7]++;
#pragma unroll
    for (int e = 0; e < E_NUM; ++e) lcnt[t * 8 + e] = c[e];
    __syncthreads();
    if (t < E_NUM) {                         // serial exclusive scan per expert
      int run = 0;
      for (int i = 0; i < 256; ++i) {
        int v = lcnt[i * 8 + t]; lcnt[i * 8 + t] = run; run += v;
      }
      cnt[t] = run;
    }
    __syncthreads();
    if (t == 0) {
      int run = 0, blk = 0;
      for (int e = 0; e < E_NUM; ++e) {
        off[e] = run;
        int padded = ((cnt[e] + BM - 1) / BM) * BM;
        pad[e] = padded;
        for (int b = 0; b < padded / BM; ++b) block_expert[blk++] = e;
        run += padded;
      }
      for (; blk < NROWBLK; ++blk) block_expert[blk] = -1;
    }
    __syncthreads();
    // assign: running counter per (thread, expert) in LDS
    for (int i = 0; i < 32; ++i) {
      int p = t * 32 + i;
      int e = topk_ids[p] & 7;
      int idx = t * 8 + e;
      int pos = off[e] + lcnt[idx];
      lcnt[idx] = lcnt[idx] + 1;
      pair_token[pos] = p >> 1;
      pos_of[p] = pos;
    }
    // pad rows point at token 0 (computed, never gathered)
    for (int e = 0; e < E_NUM; ++e) {
      int s = off[e] + cnt[e], epos = off[e] + pad[e];
      for (int r = s + t; r < epos; r += 256) pair_token[r] = 0;
    }
  } else if (bid <= 4096) {
    // ---- hs convert ----
    int i = (bid - 1) * 256 + t;
    float4 v = ((const float4*)hs)[i];
    ushort4 o;
    o.x = f2bf(v.x); o.y = f2bf(v.y); o.z = f2bf(v.z); o.w = f2bf(v.w);
    ((ushort4*)hsb)[i] = o;
  } else if (bid <= 8192) {
    // ---- w1 transpose: R=1024(K), Cc=2048(2N); 512 tiles/expert ----
    int idx = bid - 4097;
    int e = idx >> 9, rem = idx & 511;
    int cb = rem >> 4, rb = rem & 15;
    transpose_tile64(w1 + (size_t)e * 1024 * 2048, w1t + (size_t)e * 1024 * 2048,
                     1024, 2048, rb, cb, shm);
  } else {
    // ---- w2 transpose: R=1024(N), Cc=1024(K); 256 tiles/expert ----
    int idx = bid - 8193;
    int e = idx >> 8, rem = idx & 255;
    int cb = rem >> 4, rb = rem & 15;
    transpose_tile64(w2 + (size_t)e * 1024 * 1024, w2t + (size_t)e * 1024 * 1024,
                     1024, 1024, rb, cb, shm);
  }
}

// ---------------- grouped GEMM, 128x128 tile, NB B-matrices -------------------
// NB=2: fused gate|up GEMM1 -> h = silu(gate)*up.  NB=1: plain GEMM2 -> y.
// Winning schedule (r2/r4/r7/r10): 4 waves 2x2, wave 64x64(xNB), acc[NB][4][4],
// single-buffered drain loop. Its 2-3 co-resident blocks/CU provide the
// cross-block latency hiding that every explicit-pipeline variant destroyed.
// launch_bounds (256, 2/3): VGPR 104 + AGPR, ZERO spill (r9: tighter bounds
// -> 84 VGPR cap -> 206MB scratch). Zero-conflict XOR-swizzle staging via
// global_load_lds width=16 (Common-mistake #1).
// XCD chunk swizzle (T1): 72 % 8 == 0 -> bx = (b&7)*9 + (b>>3) bijective.
template <bool GATHER, int NB>
__global__ __launch_bounds__(256, NB == 2 ? 2 : 3) void gemm128(
    const u16* __restrict__ A, const u16* __restrict__ Bt, u16* __restrict__ Out,
    const int* __restrict__ pair_token, const int* __restrict__ block_expert) {
  const int bx = ((int)blockIdx.x & 7) * (NROWBLK / 8) + ((int)blockIdx.x >> 3);
  const int e = block_expert[bx];
  if (e < 0) return;
  __shared__ __align__(16) u16 As[128 * 64];
  __shared__ __align__(16) u16 Bs[NB * 128 * 64];
  const int tid = threadIdx.x;
  const int wave = tid >> 6;
  const int lane = tid & 63;
  const int wr = wave >> 1;                  // wave row-group (0..1)
  const int wc = wave & 1;                   // wave col-group (0..1)
  const int srow = wave * 8 + (lane >> 3);   // staging row within 32-row shot
  const int kc = ((lane & 7) ^ (srow & 7)) << 3;  // swizzled src chunk (elems)

  const u16* ap[4];
#pragma unroll
  for (int is = 0; is < 4; ++is) {
    int rt = is * 32 + srow;
    int grow = bx * BM + rt;
    int arow = GATHER ? pair_token[grow] : grow;
    ap[is] = A + (size_t)arow * K_DIM + kc;
  }
  const u16* bp[NB][4];
  const u16* base_e = Bt + (size_t)e * (NB * N_DIM) * K_DIM;
#pragma unroll
  for (int nb = 0; nb < NB; ++nb)
#pragma unroll
    for (int is = 0; is < 4; ++is) {
      int n = nb * N_DIM + blockIdx.y * 128 + is * 32 + srow;
      bp[nb][is] = base_e + (size_t)n * K_DIM + kc;
    }
  u16* alds = As + wave * 512;
  u16* blds = Bs + wave * 512;

  f32x4 acc[NB][4][4];
#pragma unroll
  for (int nb = 0; nb < NB; ++nb)
#pragma unroll
    for (int i = 0; i < 4; ++i)
#pragma unroll
      for (int j = 0; j < 4; ++j) acc[nb][i][j] = f32x4{0.f, 0.f, 0.f, 0.f};

  for (int k0 = 0; k0 < K_DIM; k0 += 64) {
#pragma unroll
    for (int is = 0; is < 4; ++is)
      __builtin_amdgcn_global_load_lds(GPTR(ap[is] + k0), LPTR(alds + is * 2048), 16, 0, 0);
#pragma unroll
    for (int nb = 0; nb < NB; ++nb)
#pragma unroll
      for (int is = 0; is < 4; ++is)
        __builtin_amdgcn_global_load_lds(GPTR(bp[nb][is] + k0), LPTR(blds + nb * 8192 + is * 2048), 16, 0, 0);
    __syncthreads();
#pragma unroll
    for (int ks = 0; ks < 2; ++ks) {
      const int cq = ks * 4 + (lane >> 4);
      bf16x8 af[4], bfr[NB][4];
#pragma unroll
      for (int i = 0; i < 4; ++i) {
        int row = wr * 64 + i * 16 + (lane & 15);
        af[i] = *(const bf16x8*)&As[row * 64 + ((cq ^ (row & 7)) << 3)];
      }
#pragma unroll
      for (int nb = 0; nb < NB; ++nb)
#pragma unroll
        for (int j = 0; j < 4; ++j) {
          int n = wc * 64 + j * 16 + (lane & 15);
          bfr[nb][j] = *(const bf16x8*)&Bs[nb * 8192 + n * 64 + ((cq ^ (n & 7)) << 3)];
        }
#pragma unroll
      for (int nb = 0; nb < NB; ++nb)
#pragma unroll
        for (int i = 0; i < 4; ++i)
#pragma unroll
          for (int j = 0; j < 4; ++j)
            acc[nb][i][j] = __builtin_amdgcn_mfma_f32_16x16x32_bf16(af[i], bfr[nb][j], acc[nb][i][j], 0, 0, 0);
    }
    __syncthreads();
  }

  // epilogue: C/D layout col=lane&15, row=(lane>>4)*4+reg (m89/m91-verified)
  const size_t rbase = (size_t)bx * BM + wr * 64 + ((lane >> 4) * 4);
  const int cbase = blockIdx.y * 128 + wc * 64 + (lane & 15);
#pragma unroll
  for (int i = 0; i < 4; ++i)
#pragma unroll
    for (int j = 0; j < 4; ++j)
#pragma unroll
      for (int r = 0; r < 4; ++r) {
        float v;
        if (NB == 2) {
          float g = acc[0][i][j][r], u = acc[1][i][j][r];
          v = g * u / (1.f + __expf(-g));
        } else {
          v = acc[0][i][j][r];
        }
        Out[(rbase + i * 16 + r) * N_DIM + cbase + j * 16] = f2bf(v);
      }
}

// ---------------- gather: out[m] = w0*y[pos0] + w1*y[pos1] --------------------
__global__ __launch_bounds__(256) void gather_kernel(
    const u16* __restrict__ y, const float* __restrict__ tw,
    const int* __restrict__ pos_of, float* __restrict__ out) {
  int m = blockIdx.x;
  int k = threadIdx.x * 4;
  int p0 = pos_of[m * 2 + 0], p1 = pos_of[m * 2 + 1];
  float w0 = tw[m * 2 + 0], w1 = tw[m * 2 + 1];
  ushort4 y0 = *(const ushort4*)&y[(size_t)p0 * 1024 + k];
  ushort4 y1 = *(const ushort4*)&y[(size_t)p1 * 1024 + k];
  float4 o;
  o.x = w0 * bf2f(y0.x) + w1 * bf2f(y1.x);
  o.y = w0 * bf2f(y0.y) + w1 * bf2f(y1.y);
  o.z = w0 * bf2f(y0.z) + w1 * bf2f(y1.z);
  o.w = w0 * bf2f(y0.w) + w1 * bf2f(y1.w);
  *(float4*)&out[(size_t)m * 1024 + k] = o;
}

extern "C" void kernel_launch(void* const* d_in, const int* in_sizes, int n_in,
                              void* d_out, int out_size, void* d_ws, size_t ws_size,
                              hipStream_t stream) {
  const float* hs = (const float*)d_in[0];
  const float* w1 = (const float*)d_in[1];
  const float* w2 = (const float*)d_in[2];
  const float* tw = (const float*)d_in[3];
  const int* tids = (const int*)d_in[4];
  float* out = (float*)d_out;

  char* ws = (char*)d_ws;
  u16* hsb = (u16*)(ws);                                 //  8 MB  (M,K) bf16
  u16* w1t = (u16*)(ws + (size_t)(8u << 20));            // 32 MB  (E,2N,K) bf16
  u16* w2t = (u16*)(ws + (size_t)(40u << 20));           // 16 MB  (E,K,N)  bf16
  u16* h   = (u16*)(ws + (size_t)(56u << 20));           // 18.9 MB (ROWS_CAP,N)
  u16* y   = (u16*)(ws + (size_t)(76u << 20));           // 18.9 MB (ROWS_CAP,K)
  int* pair_token   = (int*)(ws + (size_t)(96u << 20));
  int* pos_of       = (int*)(ws + (size_t)(96u << 20) + 64 * 1024);
  int* block_expert = (int*)(ws + (size_t)(96u << 20) + 128 * 1024);

  // 4 dispatches (frontier structure): prep, GEMM1, GEMM2, gather
  prep_route_kernel<<<10241, 256, 0, stream>>>(
      hs, w1, w2, tids, hsb, w1t, w2t, pair_token, pos_of, block_expert);
  gemm128<true, 2><<<dim3(NROWBLK, 8), 256, 0, stream>>>(hsb, w1t, h, pair_token, block_expert);
  gemm128<false, 1><<<dim3(NROWBLK, 8), 256, 0, stream>>>(h, w2t, y, pair_token, block_expert);
  gather_kernel<<<4096, 256, 0, stream>>>(y, tw, pos_of, out);
}